// Round 13
// baseline (224.812 us; speedup 1.0000x reference)
//
#include <hip/hip_runtime.h>

// MultiHeadContrastive on MI355X (gfx950).
// prep (fused zero + weight transpose/convert + label meta)
//   -> GEMM1 (X@W1+b, relu, bf16 H; 8 waves/block, BK=64, reg-prefetch)
//   -> GEMM2 (+bias, L2-normalize, bf16 Z; FUSED class sums S_c via LDS)
//   -> sim2: ONE launch, symmetric tile-pairs, MERGED HEADS (one barrier pair
//        shelters both heads' MFMA+exp: 48 MFMA + 64 exp per stage), 2 gaps
//        per block. Row sums flushed once/block, col sums (3 vals) per tile.
//   -> finalize (per-row losses, diag corrections, weighted reduce,
//                FUSED writeout via last-block ticket).           5 launches.

typedef __attribute__((ext_vector_type(8))) short bs8;   // 8 x bf16 (4 VGPRs)
typedef __attribute__((ext_vector_type(4))) float f4;    // MFMA accumulator

#define MFMA_BF16(a, b, c) __builtin_amdgcn_mfma_f32_16x16x32_bf16((a), (b), (c), 0, 0, 0)

#if defined(__has_builtin)
#if __has_builtin(__builtin_amdgcn_exp2f)
#define EXP2F(x) __builtin_amdgcn_exp2f(x)
#endif
#endif
#ifndef EXP2F
#define EXP2F(x) exp2f(x)
#endif

#define K_LOG2E 7.2134752044448170f   // 5 * log2(e), for exp(sim/tau) = 2^(c*K)

__device__ __forceinline__ unsigned short f2bf(float f) {
  unsigned int u = __float_as_uint(f);
  u = (u + 0x7fffu + ((u >> 16) & 1u)) >> 16;   // RNE
  return (unsigned short)u;
}
__device__ __forceinline__ float bf2f(unsigned short s) {
  return __uint_as_float(((unsigned int)s) << 16);
}

// ---------------- workspace layout (bytes) ----------------
constexpr size_t O_W1T  = 0;          // 512x1024 bf16 (rows 0..255 fg, 256..511 cls), W1T[n][k]
constexpr size_t O_W2TF = 1048576;    // 64x256 bf16, W2Tf[d][h]
constexpr size_t O_W2TC = 1081344;    // 128x256 bf16
constexpr size_t O_H    = 1146880;    // 8192x512 bf16 (cols 0..255 fg-h, 256..511 cls-h)
constexpr size_t O_ZF   = 9535488;    // 8192x64 bf16 normalized
constexpr size_t O_ZC   = 10584064;   // 8192x128 bf16 normalized
constexpr size_t O_SCLS = 12681216;   // 32x128 f32 class sums (rows 1..20 used;
                                      //   row 31 col 0 = finalize ticket) [zeroed]
constexpr size_t O_ROWD = 12697600;   // 8192 f32 denom (fg head)   [zeroed]
constexpr size_t O_ROWN = 12730368;   // 8192 f32 numer (fg head)   [zeroed]
constexpr size_t O_ROWS = 12763136;   // 8192 f32 sum-exp (cls)     [zeroed]
constexpr size_t O_SCAL = 12795904;   // 4 f32: w_fg, wl_fg, w_c, wl_c [zeroed]
constexpr size_t O_HIST = 12795920;   // 32 int  (direct store by prep meta block)
constexpr size_t O_NFG  = 12796048;   // 1 int   (direct store by prep meta block)
constexpr size_t O_CNT  = O_SCLS + 31 * 128 * 4;   // ticket counter (in zeroed Scls row 31)
constexpr int ZERO_WORDS = (int)((O_SCAL + 16 - O_SCLS) / 4);  // 28676

// ---------------- prep: fused zero + transpose/convert + meta ----------------
// blocks 0..139: weight transpose tiles; block 140: label meta; 141..253: zero.
__global__ void __launch_bounds__(256) prep_kernel(
    const float* __restrict__ fgw1, const float* __restrict__ clsw1,
    const float* __restrict__ fgw2, const float* __restrict__ clsw2,
    const int* __restrict__ labels,
    unsigned short* __restrict__ W1T, unsigned short* __restrict__ W2Tf,
    unsigned short* __restrict__ W2Tc,
    int* __restrict__ hist, int* __restrict__ nfg, float* __restrict__ zp) {
  const int b = blockIdx.x;
  const int t = threadIdx.x;

  if (b >= 141) {                     // ---- zero accumulators ----
    const int i = (b - 141) * 256 + t;
    if (i < ZERO_WORDS) zp[i] = 0.f;
    return;
  }
  if (b == 140) {                     // ---- meta: hist + nfg, single block ----
    __shared__ int sh[33];
    if (t < 33) sh[t] = 0;
    __syncthreads();
    for (int it = 0; it < 32; it++) {
      const int lab = labels[it * 256 + t];
      if (lab >= 0 && lab < 32) atomicAdd(&sh[lab], 1);   // ~ignore
      if (lab > 0) atomicAdd(&sh[32], 1);                 // fg count
    }
    __syncthreads();
    if (t < 32) hist[t] = sh[t];
    if (t == 32) *nfg = sh[32];
    return;
  }
  // ---- weight transpose + f32->bf16 ----
  // m0: 64 tiles, m1: 64, m2: 4, m3: 8  (total 140)
  int m, tb;
  if (b < 64)       { m = 0; tb = b; }
  else if (b < 128) { m = 1; tb = b - 64; }
  else if (b < 132) { m = 2; tb = b - 128; }
  else              { m = 3; tb = b - 132; }
  __shared__ float tile[64][65];
  const float* src;
  unsigned short* dst;
  int R, C;
  if (m == 0)      { src = fgw1;  dst = W1T;              R = 1024; C = 256; }
  else if (m == 1) { src = clsw1; dst = W1T + 256 * 1024; R = 1024; C = 256; }
  else if (m == 2) { src = fgw2;  dst = W2Tf;             R = 256;  C = 64;  }
  else             { src = clsw2; dst = W2Tc;             R = 256;  C = 128; }
  const int cT = C >> 6;
  const int r0 = (tb / cT) << 6, c0 = (tb % cT) << 6;
  {
    const int rr = t >> 4, cc = (t & 15) << 2;
#pragma unroll
    for (int i = 0; i < 4; i++) {
      float4 v = *(const float4*)(src + (size_t)(r0 + rr + i * 16) * C + c0 + cc);
      tile[rr + i * 16][cc] = v.x; tile[rr + i * 16][cc + 1] = v.y;
      tile[rr + i * 16][cc + 2] = v.z; tile[rr + i * 16][cc + 3] = v.w;
    }
  }
  __syncthreads();
  {
    const int dr = t >> 2, dc = (t & 3) << 4;
    bs8 o0, o1;
#pragma unroll
    for (int j = 0; j < 8; j++) o0[j] = (short)f2bf(tile[dc + j][dr]);
#pragma unroll
    for (int j = 0; j < 8; j++) o1[j] = (short)f2bf(tile[dc + 8 + j][dr]);
    unsigned short* dp = dst + (size_t)(c0 + dr) * R + r0 + dc;
    *(bs8*)dp = o0;
    *(bs8*)(dp + 8) = o1;
  }
}

// ---------------- GEMM1: H = relu(X @ W1 + b1), both heads ----------------
// grid (128, 4) x 512 threads (8 waves): 64-row x 128-col tiles, BK=64.
// Wave w: rows (w&3)*16, cols (w>>2)*64. Register-prefetch pipelined.
__global__ void __launch_bounds__(512) gemm1_kernel(
    const float* __restrict__ X, const unsigned short* __restrict__ W1T,
    const float* __restrict__ b1f, const float* __restrict__ b1c,
    unsigned short* __restrict__ H) {
  __shared__ __align__(16) unsigned short lA[64 * 72];
  __shared__ __align__(16) unsigned short lB[128 * 72];
  const int t = threadIdx.x;
  const int w = t >> 6, lane = t & 63, ln = lane & 15, quad = lane >> 4;
  const int wr = (w & 3) * 16, wc = (w >> 2) * 64;
  const int m0 = blockIdx.x * 64, n0 = blockIdx.y * 128;

  const int ar = t >> 3, ac = (t & 7) * 8;
  const int br = t >> 2, bc = (t & 3) * 16;
  const float* xbase = X + (size_t)(m0 + ar) * 1024 + ac;
  const unsigned short* bbase = W1T + (size_t)(n0 + br) * 1024 + bc;

  float4 xa[2];
  bs8 xb[2];
#pragma unroll
  for (int i = 0; i < 2; i++) xa[i] = *(const float4*)(xbase + i * 4);
#pragma unroll
  for (int i = 0; i < 2; i++) xb[i] = *(const bs8*)(bbase + i * 8);

  f4 acc[4];
#pragma unroll
  for (int s = 0; s < 4; s++) acc[s] = (f4){0.f, 0.f, 0.f, 0.f};

  for (int ks = 0; ks < 16; ks++) {
    {
      bs8 av;
      av[0] = (short)f2bf(xa[0].x); av[1] = (short)f2bf(xa[0].y);
      av[2] = (short)f2bf(xa[0].z); av[3] = (short)f2bf(xa[0].w);
      av[4] = (short)f2bf(xa[1].x); av[5] = (short)f2bf(xa[1].y);
      av[6] = (short)f2bf(xa[1].z); av[7] = (short)f2bf(xa[1].w);
      *(bs8*)&lA[ar * 72 + ac] = av;
      unsigned short* bp = &lB[br * 72 + bc];
      *(bs8*)(bp) = xb[0];
      *(bs8*)(bp + 8) = xb[1];
    }
    __syncthreads();
    if (ks < 15) {
      const int k1 = (ks + 1) * 64;
#pragma unroll
      for (int i = 0; i < 2; i++) xa[i] = *(const float4*)(xbase + k1 + i * 4);
#pragma unroll
      for (int i = 0; i < 2; i++) xb[i] = *(const bs8*)(bbase + k1 + i * 8);
    }
#pragma unroll
    for (int kk = 0; kk < 2; kk++) {
      bs8 af = *(const bs8*)&lA[(wr + ln) * 72 + kk * 32 + quad * 8];
#pragma unroll
      for (int s = 0; s < 4; s++) {
        bs8 bf = *(const bs8*)&lB[(wc + s * 16 + ln) * 72 + kk * 32 + quad * 8];
        acc[s] = MFMA_BF16(af, bf, acc[s]);
      }
    }
    __syncthreads();
  }
#pragma unroll
  for (int s = 0; s < 4; s++) {
    const int n = n0 + wc + s * 16 + ln;
    const float b = (n < 256) ? b1f[n] : b1c[n - 256];
#pragma unroll
    for (int r = 0; r < 4; r++) {
      float v = fmaxf(acc[s][r] + b, 0.f);
      H[(size_t)(m0 + wr + quad * 4 + r) * 512 + n] = f2bf(v);
    }
  }
}

// ---------------- GEMM2: Z = normalize(H @ W2 + b2), FUSED class sums ----------------
// grid (256): 32 rows/block; waves 0,1 = fg head; waves 2,3 = cls head.
// cls waves also accumulate S_c partials into LDS sS[21][128]; block flushes
// nonzero entries with one global atomic each (classes 1..20 only).
__global__ void __launch_bounds__(256) gemm2_kernel(
    const unsigned short* __restrict__ H,
    const unsigned short* __restrict__ W2Tf, const unsigned short* __restrict__ W2Tc,
    const float* __restrict__ b2f, const float* __restrict__ b2c,
    const int* __restrict__ labels,
    unsigned short* __restrict__ Zf, unsigned short* __restrict__ Zc,
    float* __restrict__ Scls) {
  __shared__ float sS[21 * 128];
  const int t = threadIdx.x;
  for (int i = t; i < 21 * 128; i += 256) sS[i] = 0.f;
  __syncthreads();

  const int w = t >> 6, lane = t & 63, ln = lane & 15, quad = lane >> 4;
  const int rw = blockIdx.x * 32 + (w & 1) * 16;

  if (w < 2) {  // fg head: K=256 (H cols 0..255), N=64
    const unsigned short* hrow = H + (size_t)(rw + ln) * 512;
    f4 acc[4];
#pragma unroll
    for (int s = 0; s < 4; s++) acc[s] = (f4){0.f, 0.f, 0.f, 0.f};
#pragma unroll
    for (int ks = 0; ks < 8; ks++) {
      bs8 af = *(const bs8*)(hrow + ks * 32 + quad * 8);
#pragma unroll
      for (int s = 0; s < 4; s++) {
        bs8 bf = *(const bs8*)(W2Tf + (size_t)(s * 16 + ln) * 256 + ks * 32 + quad * 8);
        acc[s] = MFMA_BF16(af, bf, acc[s]);
      }
    }
    float ss[4] = {0.f, 0.f, 0.f, 0.f};
#pragma unroll
    for (int s = 0; s < 4; s++) {
      float b = b2f[s * 16 + ln];
#pragma unroll
      for (int r = 0; r < 4; r++) {
        acc[s][r] += b;
        ss[r] = fmaf(acc[s][r], acc[s][r], ss[r]);
      }
    }
#pragma unroll
    for (int r = 0; r < 4; r++) {
#pragma unroll
      for (int off = 1; off < 16; off <<= 1) ss[r] += __shfl_xor(ss[r], off, 64);
      float sc = 1.f / fmaxf(sqrtf(ss[r]), 1e-8f);
#pragma unroll
      for (int s = 0; s < 4; s++)
        Zf[(size_t)(rw + quad * 4 + r) * 64 + s * 16 + ln] = f2bf(acc[s][r] * sc);
    }
  } else {  // cls head: K=256 (H cols 256..511), N=128
    const unsigned short* hrow = H + (size_t)(rw + ln) * 512 + 256;
    f4 acc[8];
#pragma unroll
    for (int s = 0; s < 8; s++) acc[s] = (f4){0.f, 0.f, 0.f, 0.f};
#pragma unroll
    for (int ks = 0; ks < 8; ks++) {
      bs8 af = *(const bs8*)(hrow + ks * 32 + quad * 8);
#pragma unroll
      for (int s = 0; s < 8; s++) {
        bs8 bf = *(const bs8*)(W2Tc + (size_t)(s * 16 + ln) * 256 + ks * 32 + quad * 8);
        acc[s] = MFMA_BF16(af, bf, acc[s]);
      }
    }
    float ss[4] = {0.f, 0.f, 0.f, 0.f};
#pragma unroll
    for (int s = 0; s < 8; s++) {
      float b = b2c[s * 16 + ln];
#pragma unroll
      for (int r = 0; r < 4; r++) {
        acc[s][r] += b;
        ss[r] = fmaf(acc[s][r], acc[s][r], ss[r]);
      }
    }
#pragma unroll
    for (int r = 0; r < 4; r++) {
#pragma unroll
      for (int off = 1; off < 16; off <<= 1) ss[r] += __shfl_xor(ss[r], off, 64);
      float sc = 1.f / fmaxf(sqrtf(ss[r]), 1e-8f);
      const int lab = labels[rw + quad * 4 + r];
#pragma unroll
      for (int s = 0; s < 8; s++) {
        const unsigned short us = f2bf(acc[s][r] * sc);
        Zc[(size_t)(rw + quad * 4 + r) * 128 + s * 16 + ln] = us;
        if (lab > 0 && lab < 21) atomicAdd(&sS[lab * 128 + s * 16 + ln], bf2f(us));
      }
    }
  }

  __syncthreads();
  for (int i = t; i < 20 * 128; i += 256) {    // flush classes 1..20
    const float v = sS[128 + i];
    if (v != 0.f) atomicAdd(&Scls[128 + i], v);
  }
}

// ---------------- sim2: MERGED HEADS, symmetric tile-pairs, 2 gaps/block ----------------
// grid (64, 17). y<16: gaps d in {2y, 2y+1} (y=0 includes diagonal, row-side
// only); y==16: d=32 only (bi<32). Per block: both heads' A-frags loaded once;
// per ct-stage ONE barrier pair shelters sZf+sZc staging and BOTH heads'
// compute (48 MFMA + 64 exp). Row sums (D,N,S) flushed once per block;
// col sums (3 values) flushed per off-diagonal tile.
__global__ void __launch_bounds__(256) sim2_kernel(
    const unsigned short* __restrict__ Zf, const unsigned short* __restrict__ Zc,
    const int* __restrict__ labels,
    float* __restrict__ rowD, float* __restrict__ rowN, float* __restrict__ rowS) {
  const int bi = blockIdx.x, y = blockIdx.y;
  int dlo, dhi;
  if (y < 16) { dlo = 2 * y; dhi = 2 * y + 1; }
  else        { dlo = 32;    dhi = 32; if (bi >= 32) return; }

  __shared__ __align__(16) unsigned short sZf[64 * 72];   // 9216 B
  __shared__ __align__(16) unsigned short sZc[64 * 136];  // 17408 B
  __shared__ float sFg[64];                               // 256 B
  __shared__ float sCol[4][2][4][16][3];                  // 6144 B  [wave][ct][s][ln][{d,n,s}]
  const int t = threadIdx.x;
  const int w = t >> 6, lane = t & 63, ln = lane & 15, quad = lane >> 4;
  const int rbase = bi * 128 + w * 32;

  // A-fragments for both heads + fg flags of this thread's 8 rows
  bs8 afg[2][2], acl[2][4];
  float fgr[2][4];
#pragma unroll
  for (int rs = 0; rs < 2; rs++) {
    const unsigned short* zf = Zf + (size_t)(rbase + rs * 16 + ln) * 64;
    const unsigned short* zc = Zc + (size_t)(rbase + rs * 16 + ln) * 128;
#pragma unroll
    for (int s = 0; s < 2; s++) afg[rs][s] = *(const bs8*)(zf + s * 32 + quad * 8);
#pragma unroll
    for (int s = 0; s < 4; s++) acl[rs][s] = *(const bs8*)(zc + s * 32 + quad * 8);
#pragma unroll
    for (int r = 0; r < 4; r++)
      fgr[rs][r] = (labels[rbase + rs * 16 + quad * 4 + r] > 0) ? 1.f : 0.f;
  }

  float dacc[2][4] = {}, nacc[2][4] = {}, sacc[2][4] = {};   // row side, block-persistent

  for (int d = dlo; d <= dhi; d++) {
    const int bj = (bi + d) & 63;
    float cd[2][4] = {}, cn[2][4] = {}, cs[2][4] = {};       // col side, per tile

#pragma unroll
    for (int ct = 0; ct < 2; ct++) {
      const int c0 = bj * 128 + ct * 64;
      __syncthreads();
#pragma unroll
      for (int i = 0; i < 2; i++) {          // stage sZf: 64x64 bf16
        int ch = t + i * 256;
        int j = ch >> 3, c8 = (ch & 7) * 8;
        *(bs8*)&sZf[j * 72 + c8] = *(const bs8*)(Zf + (size_t)(c0 + j) * 64 + c8);
      }
#pragma unroll
      for (int i = 0; i < 4; i++) {          // stage sZc: 64x128 bf16
        int ch = t + i * 256;
        int j = ch >> 4, c8 = (ch & 15) * 8;
        *(bs8*)&sZc[j * 136 + c8] = *(const bs8*)(Zc + (size_t)(c0 + j) * 128 + c8);
      }
      if (t < 64) sFg[t] = (labels[c0 + t] > 0) ? 1.f : 0.f;
      __syncthreads();

#pragma unroll
      for (int s = 0; s < 4; s++) {
        const int lcol = s * 16 + ln;
        const float fgc = sFg[lcol];
        // fg head (K=64)
        bs8 b0 = *(const bs8*)&sZf[lcol * 72 + quad * 8];
        bs8 b1 = *(const bs8*)&sZf[lcol * 72 + 32 + quad * 8];
#pragma unroll
        for (int rs = 0; rs < 2; rs++) {
          f4 c = {0.f, 0.f, 0.f, 0.f};
          c = MFMA_BF16(afg[rs][0], b0, c);
          c = MFMA_BF16(afg[rs][1], b1, c);
#pragma unroll
          for (int r = 0; r < 4; r++) {
            float e = EXP2F(c[r] * K_LOG2E);
            dacc[rs][r] += e;
            nacc[rs][r] = fmaf(fgc, e, nacc[rs][r]);
            cd[ct][s] += e;
            cn[ct][s] = fmaf(fgr[rs][r], e, cn[ct][s]);
          }
        }
        // cls head (K=128)
        bs8 bc0 = *(const bs8*)&sZc[lcol * 136 + quad * 8];
        bs8 bc1 = *(const bs8*)&sZc[lcol * 136 + 32 + quad * 8];
        bs8 bc2 = *(const bs8*)&sZc[lcol * 136 + 64 + quad * 8];
        bs8 bc3 = *(const bs8*)&sZc[lcol * 136 + 96 + quad * 8];
#pragma unroll
        for (int rs = 0; rs < 2; rs++) {
          f4 c = {0.f, 0.f, 0.f, 0.f};
          c = MFMA_BF16(acl[rs][0], bc0, c);
          c = MFMA_BF16(acl[rs][1], bc1, c);
          c = MFMA_BF16(acl[rs][2], bc2, c);
          c = MFMA_BF16(acl[rs][3], bc3, c);
#pragma unroll
          for (int r = 0; r < 4; r++) {
            float e = EXP2F(c[r] * K_LOG2E);
            sacc[rs][r] += e;
            cs[ct][s] += e;
          }
        }
      }
    }

    // col side -> rows of J (per off-diagonal tile): 3 values
    if (d != 0) {
      __syncthreads();                       // prior sCol readers done
#pragma unroll
      for (int ct = 0; ct < 2; ct++)
#pragma unroll
        for (int s = 0; s < 4; s++) {
          float dv = cd[ct][s], nv = cn[ct][s], sv = cs[ct][s];
#pragma unroll
          for (int off = 16; off < 64; off <<= 1) {
            dv += __shfl_xor(dv, off, 64);
            nv += __shfl_xor(nv, off, 64);
            sv += __shfl_xor(sv, off, 64);
          }
          if (quad == 0) {
            sCol[w][ct][s][ln][0] = dv;
            sCol[w][ct][s][ln][1] = nv;
            sCol[w][ct][s][ln][2] = sv;
          }
        }
      __syncthreads();
      if (t < 128) {
        const int ct = t >> 6, s = (t >> 4) & 3, lm = t & 15;
        float dv = 0.f, nv = 0.f, sv = 0.f;
#pragma unroll
        for (int ww = 0; ww < 4; ww++) {
          dv += sCol[ww][ct][s][lm][0];
          nv += sCol[ww][ct][s][lm][1];
          sv += sCol[ww][ct][s][lm][2];
        }
        const int col = bj * 128 + t;
        atomicAdd(&rowD[col], dv);
        atomicAdd(&rowN[col], nv);
        atomicAdd(&rowS[col], sv);
      }
    }
  }

  // row side -> rows of I (once per block): 3 values
#pragma unroll
  for (int rs = 0; rs < 2; rs++)
#pragma unroll
    for (int r = 0; r < 4; r++) {
      float dv = dacc[rs][r], nv = nacc[rs][r], sv = sacc[rs][r];
#pragma unroll
      for (int off = 1; off < 16; off <<= 1) {
        dv += __shfl_xor(dv, off, 64);
        nv += __shfl_xor(nv, off, 64);
        sv += __shfl_xor(sv, off, 64);
      }
      if (ln == 0) {
        int row = rbase + rs * 16 + quad * 4 + r;
        atomicAdd(&rowD[row], dv);
        atomicAdd(&rowN[row], nv);
        atomicAdd(&rowS[row], sv);
      }
    }
}

// ---------------- per-row losses + reduction + fused writeout (ticket) ----------------
__global__ void __launch_bounds__(256) finalize_kernel(
    const unsigned short* __restrict__ Zf, const unsigned short* __restrict__ Zc,
    const int* __restrict__ labels, const float* __restrict__ ious,
    const float* __restrict__ rowD, const float* __restrict__ rowN,
    const float* __restrict__ rowS, const float* __restrict__ Scls,
    const int* __restrict__ hist, const int* __restrict__ nfg,
    float* __restrict__ scal, unsigned int* __restrict__ cnt,
    float* __restrict__ out) {
  __shared__ float red[4][4];
  const int t = threadIdx.x, w = t >> 6, lane = t & 63;
  float aw0 = 0.f, al0 = 0.f, aw1 = 0.f, al1 = 0.f;
  const int NFG = *nfg;
  for (int it = 0; it < 16; it++) {
    const int i = it * 512 + blockIdx.x * 4 + w;   // wave-uniform row
    const int lab = labels[i];
    if (lab > 0 && lab < 32) {                     // fg row
      const float iou = ious[i];
      const float iw = (iou > 0.5f) ? iou : 0.f;
      float dot = 0.f, ssq = 0.f;
#pragma unroll
      for (int p = 0; p < 2; p++) {
        const int k = lane + p * 64;
        const float z = bf2f(Zc[(size_t)i * 128 + k]);
        dot = fmaf(z, Scls[lab * 128 + k], dot);
        ssq = fmaf(z, z, ssq);
      }
      float zf = bf2f(Zf[(size_t)i * 64 + lane]);
      float ssqf = zf * zf;
#pragma unroll
      for (int off = 1; off < 64; off <<= 1) {
        dot += __shfl_xor(dot, off, 64);
        ssq += __shfl_xor(ssq, off, 64);
        ssqf += __shfl_xor(ssqf, off, 64);
      }
      if (lane == 0) {
        const float ef = EXP2F(K_LOG2E * ssqf);   // diag term exp(sim_ii/tau), fg head
        if (NFG - 1 > 0) {  // n_pos = NFG - 1 for fg rows
          const float D = rowD[i] - ef;
          const float Nn = rowN[i] - ef;
          const float loss = logf(D + 2e-8f) - logf(Nn + 1e-8f);
          aw0 += iw;
          al0 += iw * loss;
        }
        const int npc = hist[lab];
        if (npc > 0) {
          const float S = rowS[i] - EXP2F(K_LOG2E * ssq);  // remove cls diag
          const float logden = logf(S);
          // sum_log_p = sum_{pos,j!=i}(sim) - (npc-1)*logden + NEG(diag)
          const float slp = (dot - ssq) * 5.0f - (float)(npc - 1) * logden - 1e9f;
          aw1 += iw;
          al1 += iw * (-slp / ((float)npc + 1e-8f));
        }
      }
    }
  }
  if (lane == 0) { red[w][0] = aw0; red[w][1] = al0; red[w][2] = aw1; red[w][3] = al1; }
  __syncthreads();
  if (t < 4) atomicAdd(&scal[t], red[0][t] + red[1][t] + red[2][t] + red[3][t]);
  __syncthreads();
  if (t == 0) {
    __threadfence();
    const unsigned int ticket = atomicAdd(cnt, 1u);
    if (ticket == gridDim.x - 1) {               // last block: fused writeout
      __threadfence();
      const float s0 = atomicAdd(&scal[0], 0.f);
      const float s1 = atomicAdd(&scal[1], 0.f);
      const float s2 = atomicAdd(&scal[2], 0.f);
      const float s3 = atomicAdd(&scal[3], 0.f);
      out[0] = s1 / (s0 + 1e-8f);
      out[1] = s3 / (s2 + 1e-8f);
    }
  }
}

// ---------------- launch ----------------
extern "C" void kernel_launch(void* const* d_in, const int* in_sizes, int n_in,
                              void* d_out, int out_size, void* d_ws, size_t ws_size,
                              hipStream_t stream) {
  (void)in_sizes; (void)n_in; (void)out_size; (void)ws_size;
  const float* roi    = (const float*)d_in[0];
  const int*   labels = (const int*)d_in[1];
  const float* ious   = (const float*)d_in[2];
  const float* fgw1   = (const float*)d_in[3];
  const float* fgb1   = (const float*)d_in[4];
  const float* fgw2   = (const float*)d_in[5];
  const float* fgb2   = (const float*)d_in[6];
  const float* clsw1  = (const float*)d_in[7];
  const float* clsb1  = (const float*)d_in[8];
  const float* clsw2  = (const float*)d_in[9];
  const float* clsb2  = (const float*)d_in[10];

  char* ws = (char*)d_ws;
  unsigned short* W1T  = (unsigned short*)(ws + O_W1T);
  unsigned short* W2Tf = (unsigned short*)(ws + O_W2TF);
  unsigned short* W2Tc = (unsigned short*)(ws + O_W2TC);
  unsigned short* Hb   = (unsigned short*)(ws + O_H);
  unsigned short* Zf   = (unsigned short*)(ws + O_ZF);
  unsigned short* Zc   = (unsigned short*)(ws + O_ZC);
  float* Scls = (float*)(ws + O_SCLS);
  float* rowD = (float*)(ws + O_ROWD);
  float* rowN = (float*)(ws + O_ROWN);
  float* rowS = (float*)(ws + O_ROWS);
  float* scal = (float*)(ws + O_SCAL);
  unsigned int* cnt = (unsigned int*)(ws + O_CNT);
  int* hist = (int*)(ws + O_HIST);
  int* nfg  = (int*)(ws + O_NFG);
  float* out = (float*)d_out;

  hipLaunchKernelGGL(prep_kernel, dim3(254), dim3(256), 0, stream,
                     fgw1, clsw1, fgw2, clsw2, labels, W1T, W2Tf, W2Tc,
                     hist, nfg, (float*)(ws + O_SCLS));
  hipLaunchKernelGGL(gemm1_kernel, dim3(128, 4), dim3(512), 0, stream,
                     roi, W1T, fgb1, clsb1, Hb);
  hipLaunchKernelGGL(gemm2_kernel, dim3(256), dim3(256), 0, stream,
                     Hb, W2Tf, W2Tc, fgb2, clsb2, labels, Zf, Zc, Scls);
  hipLaunchKernelGGL(sim2_kernel, dim3(64, 17), dim3(256), 0, stream,
                     Zf, Zc, labels, rowD, rowN, rowS);
  hipLaunchKernelGGL(finalize_kernel, dim3(128), dim3(256), 0, stream,
                     Zf, Zc, labels, ious, rowD, rowN, rowS, Scls, hist, nfg,
                     scal, cnt, out);
}

// Round 14
// 201.649 us; speedup vs baseline: 1.1149x; 1.1149x over previous
//
#include <hip/hip_runtime.h>

// MultiHeadContrastive on MI355X (gfx950).
// prep (fused zero + weight transpose/convert + label meta)
//   -> GEMM1 (X@W1+b, relu, bf16 H; 8 waves/block, BK=64, reg-prefetch)
//   -> GEMM2 (+bias, L2-normalize, bf16 Z; FUSED class sums S_c via LDS)
//   -> sim2: ONE launch, symmetric tile-pairs, 4 gaps per block, SPLIT HEADS
//        (blockIdx.y selects head; per-head state fits ~92 VGPR — merged-head
//        variants hit 168-172 VGPR and collapse occupancy: R2/R13)
//   -> finalize (per-row losses, diag corrections, weighted reduce,
//                FUSED writeout via last-block ticket).           5 launches.

typedef __attribute__((ext_vector_type(8))) short bs8;   // 8 x bf16 (4 VGPRs)
typedef __attribute__((ext_vector_type(4))) float f4;    // MFMA accumulator

#define MFMA_BF16(a, b, c) __builtin_amdgcn_mfma_f32_16x16x32_bf16((a), (b), (c), 0, 0, 0)

#if defined(__has_builtin)
#if __has_builtin(__builtin_amdgcn_exp2f)
#define EXP2F(x) __builtin_amdgcn_exp2f(x)
#endif
#endif
#ifndef EXP2F
#define EXP2F(x) exp2f(x)
#endif

#define K_LOG2E 7.2134752044448170f   // 5 * log2(e), for exp(sim/tau) = 2^(c*K)

__device__ __forceinline__ unsigned short f2bf(float f) {
  unsigned int u = __float_as_uint(f);
  u = (u + 0x7fffu + ((u >> 16) & 1u)) >> 16;   // RNE
  return (unsigned short)u;
}
__device__ __forceinline__ float bf2f(unsigned short s) {
  return __uint_as_float(((unsigned int)s) << 16);
}

// ---------------- workspace layout (bytes) ----------------
constexpr size_t O_W1T  = 0;          // 512x1024 bf16 (rows 0..255 fg, 256..511 cls), W1T[n][k]
constexpr size_t O_W2TF = 1048576;    // 64x256 bf16, W2Tf[d][h]
constexpr size_t O_W2TC = 1081344;    // 128x256 bf16
constexpr size_t O_H    = 1146880;    // 8192x512 bf16 (cols 0..255 fg-h, 256..511 cls-h)
constexpr size_t O_ZF   = 9535488;    // 8192x64 bf16 normalized
constexpr size_t O_ZC   = 10584064;   // 8192x128 bf16 normalized
constexpr size_t O_SCLS = 12681216;   // 32x128 f32 class sums (rows 1..20 used;
                                      //   row 31 col 0 = finalize ticket) [zeroed]
constexpr size_t O_ROWD = 12697600;   // 8192 f32 denom (fg head)   [zeroed]
constexpr size_t O_ROWN = 12730368;   // 8192 f32 numer (fg head)   [zeroed]
constexpr size_t O_ROWS = 12763136;   // 8192 f32 sum-exp (cls)     [zeroed]
constexpr size_t O_SCAL = 12795904;   // 4 f32: w_fg, wl_fg, w_c, wl_c [zeroed]
constexpr size_t O_HIST = 12795920;   // 32 int  (direct store by prep meta block)
constexpr size_t O_NFG  = 12796048;   // 1 int   (direct store by prep meta block)
constexpr size_t O_CNT  = O_SCLS + 31 * 128 * 4;   // ticket counter (in zeroed Scls row 31)
constexpr int ZERO_WORDS = (int)((O_SCAL + 16 - O_SCLS) / 4);  // 28676

// ---------------- prep: fused zero + transpose/convert + meta ----------------
// blocks 0..139: weight transpose tiles; block 140: label meta; 141..253: zero.
__global__ void __launch_bounds__(256) prep_kernel(
    const float* __restrict__ fgw1, const float* __restrict__ clsw1,
    const float* __restrict__ fgw2, const float* __restrict__ clsw2,
    const int* __restrict__ labels,
    unsigned short* __restrict__ W1T, unsigned short* __restrict__ W2Tf,
    unsigned short* __restrict__ W2Tc,
    int* __restrict__ hist, int* __restrict__ nfg, float* __restrict__ zp) {
  const int b = blockIdx.x;
  const int t = threadIdx.x;

  if (b >= 141) {                     // ---- zero accumulators ----
    const int i = (b - 141) * 256 + t;
    if (i < ZERO_WORDS) zp[i] = 0.f;
    return;
  }
  if (b == 140) {                     // ---- meta: hist + nfg, single block ----
    __shared__ int sh[33];
    if (t < 33) sh[t] = 0;
    __syncthreads();
    for (int it = 0; it < 32; it++) {
      const int lab = labels[it * 256 + t];
      if (lab >= 0 && lab < 32) atomicAdd(&sh[lab], 1);   // ~ignore
      if (lab > 0) atomicAdd(&sh[32], 1);                 // fg count
    }
    __syncthreads();
    if (t < 32) hist[t] = sh[t];
    if (t == 32) *nfg = sh[32];
    return;
  }
  // ---- weight transpose + f32->bf16 ----
  // m0: 64 tiles, m1: 64, m2: 4, m3: 8  (total 140)
  int m, tb;
  if (b < 64)       { m = 0; tb = b; }
  else if (b < 128) { m = 1; tb = b - 64; }
  else if (b < 132) { m = 2; tb = b - 128; }
  else              { m = 3; tb = b - 132; }
  __shared__ float tile[64][65];
  const float* src;
  unsigned short* dst;
  int R, C;
  if (m == 0)      { src = fgw1;  dst = W1T;              R = 1024; C = 256; }
  else if (m == 1) { src = clsw1; dst = W1T + 256 * 1024; R = 1024; C = 256; }
  else if (m == 2) { src = fgw2;  dst = W2Tf;             R = 256;  C = 64;  }
  else             { src = clsw2; dst = W2Tc;             R = 256;  C = 128; }
  const int cT = C >> 6;
  const int r0 = (tb / cT) << 6, c0 = (tb % cT) << 6;
  {
    const int rr = t >> 4, cc = (t & 15) << 2;
#pragma unroll
    for (int i = 0; i < 4; i++) {
      float4 v = *(const float4*)(src + (size_t)(r0 + rr + i * 16) * C + c0 + cc);
      tile[rr + i * 16][cc] = v.x; tile[rr + i * 16][cc + 1] = v.y;
      tile[rr + i * 16][cc + 2] = v.z; tile[rr + i * 16][cc + 3] = v.w;
    }
  }
  __syncthreads();
  {
    const int dr = t >> 2, dc = (t & 3) << 4;
    bs8 o0, o1;
#pragma unroll
    for (int j = 0; j < 8; j++) o0[j] = (short)f2bf(tile[dc + j][dr]);
#pragma unroll
    for (int j = 0; j < 8; j++) o1[j] = (short)f2bf(tile[dc + 8 + j][dr]);
    unsigned short* dp = dst + (size_t)(c0 + dr) * R + r0 + dc;
    *(bs8*)dp = o0;
    *(bs8*)(dp + 8) = o1;
  }
}

// ---------------- GEMM1: H = relu(X @ W1 + b1), both heads ----------------
// grid (128, 4) x 512 threads (8 waves): 64-row x 128-col tiles, BK=64.
// Wave w: rows (w&3)*16, cols (w>>2)*64. Register-prefetch pipelined.
__global__ void __launch_bounds__(512) gemm1_kernel(
    const float* __restrict__ X, const unsigned short* __restrict__ W1T,
    const float* __restrict__ b1f, const float* __restrict__ b1c,
    unsigned short* __restrict__ H) {
  __shared__ __align__(16) unsigned short lA[64 * 72];
  __shared__ __align__(16) unsigned short lB[128 * 72];
  const int t = threadIdx.x;
  const int w = t >> 6, lane = t & 63, ln = lane & 15, quad = lane >> 4;
  const int wr = (w & 3) * 16, wc = (w >> 2) * 64;
  const int m0 = blockIdx.x * 64, n0 = blockIdx.y * 128;

  const int ar = t >> 3, ac = (t & 7) * 8;
  const int br = t >> 2, bc = (t & 3) * 16;
  const float* xbase = X + (size_t)(m0 + ar) * 1024 + ac;
  const unsigned short* bbase = W1T + (size_t)(n0 + br) * 1024 + bc;

  float4 xa[2];
  bs8 xb[2];
#pragma unroll
  for (int i = 0; i < 2; i++) xa[i] = *(const float4*)(xbase + i * 4);
#pragma unroll
  for (int i = 0; i < 2; i++) xb[i] = *(const bs8*)(bbase + i * 8);

  f4 acc[4];
#pragma unroll
  for (int s = 0; s < 4; s++) acc[s] = (f4){0.f, 0.f, 0.f, 0.f};

  for (int ks = 0; ks < 16; ks++) {
    {
      bs8 av;
      av[0] = (short)f2bf(xa[0].x); av[1] = (short)f2bf(xa[0].y);
      av[2] = (short)f2bf(xa[0].z); av[3] = (short)f2bf(xa[0].w);
      av[4] = (short)f2bf(xa[1].x); av[5] = (short)f2bf(xa[1].y);
      av[6] = (short)f2bf(xa[1].z); av[7] = (short)f2bf(xa[1].w);
      *(bs8*)&lA[ar * 72 + ac] = av;
      unsigned short* bp = &lB[br * 72 + bc];
      *(bs8*)(bp) = xb[0];
      *(bs8*)(bp + 8) = xb[1];
    }
    __syncthreads();
    if (ks < 15) {
      const int k1 = (ks + 1) * 64;
#pragma unroll
      for (int i = 0; i < 2; i++) xa[i] = *(const float4*)(xbase + k1 + i * 4);
#pragma unroll
      for (int i = 0; i < 2; i++) xb[i] = *(const bs8*)(bbase + k1 + i * 8);
    }
#pragma unroll
    for (int kk = 0; kk < 2; kk++) {
      bs8 af = *(const bs8*)&lA[(wr + ln) * 72 + kk * 32 + quad * 8];
#pragma unroll
      for (int s = 0; s < 4; s++) {
        bs8 bf = *(const bs8*)&lB[(wc + s * 16 + ln) * 72 + kk * 32 + quad * 8];
        acc[s] = MFMA_BF16(af, bf, acc[s]);
      }
    }
    __syncthreads();
  }
#pragma unroll
  for (int s = 0; s < 4; s++) {
    const int n = n0 + wc + s * 16 + ln;
    const float b = (n < 256) ? b1f[n] : b1c[n - 256];
#pragma unroll
    for (int r = 0; r < 4; r++) {
      float v = fmaxf(acc[s][r] + b, 0.f);
      H[(size_t)(m0 + wr + quad * 4 + r) * 512 + n] = f2bf(v);
    }
  }
}

// ---------------- GEMM2: Z = normalize(H @ W2 + b2), FUSED class sums ----------------
// grid (256): 32 rows/block; waves 0,1 = fg head; waves 2,3 = cls head.
// cls waves also accumulate S_c partials into LDS sS[21][128]; block flushes
// nonzero entries with one global atomic each (classes 1..20 only).
__global__ void __launch_bounds__(256) gemm2_kernel(
    const unsigned short* __restrict__ H,
    const unsigned short* __restrict__ W2Tf, const unsigned short* __restrict__ W2Tc,
    const float* __restrict__ b2f, const float* __restrict__ b2c,
    const int* __restrict__ labels,
    unsigned short* __restrict__ Zf, unsigned short* __restrict__ Zc,
    float* __restrict__ Scls) {
  __shared__ float sS[21 * 128];
  const int t = threadIdx.x;
  for (int i = t; i < 21 * 128; i += 256) sS[i] = 0.f;
  __syncthreads();

  const int w = t >> 6, lane = t & 63, ln = lane & 15, quad = lane >> 4;
  const int rw = blockIdx.x * 32 + (w & 1) * 16;

  if (w < 2) {  // fg head: K=256 (H cols 0..255), N=64
    const unsigned short* hrow = H + (size_t)(rw + ln) * 512;
    f4 acc[4];
#pragma unroll
    for (int s = 0; s < 4; s++) acc[s] = (f4){0.f, 0.f, 0.f, 0.f};
#pragma unroll
    for (int ks = 0; ks < 8; ks++) {
      bs8 af = *(const bs8*)(hrow + ks * 32 + quad * 8);
#pragma unroll
      for (int s = 0; s < 4; s++) {
        bs8 bf = *(const bs8*)(W2Tf + (size_t)(s * 16 + ln) * 256 + ks * 32 + quad * 8);
        acc[s] = MFMA_BF16(af, bf, acc[s]);
      }
    }
    float ss[4] = {0.f, 0.f, 0.f, 0.f};
#pragma unroll
    for (int s = 0; s < 4; s++) {
      float b = b2f[s * 16 + ln];
#pragma unroll
      for (int r = 0; r < 4; r++) {
        acc[s][r] += b;
        ss[r] = fmaf(acc[s][r], acc[s][r], ss[r]);
      }
    }
#pragma unroll
    for (int r = 0; r < 4; r++) {
#pragma unroll
      for (int off = 1; off < 16; off <<= 1) ss[r] += __shfl_xor(ss[r], off, 64);
      float sc = 1.f / fmaxf(sqrtf(ss[r]), 1e-8f);
#pragma unroll
      for (int s = 0; s < 4; s++)
        Zf[(size_t)(rw + quad * 4 + r) * 64 + s * 16 + ln] = f2bf(acc[s][r] * sc);
    }
  } else {  // cls head: K=256 (H cols 256..511), N=128
    const unsigned short* hrow = H + (size_t)(rw + ln) * 512 + 256;
    f4 acc[8];
#pragma unroll
    for (int s = 0; s < 8; s++) acc[s] = (f4){0.f, 0.f, 0.f, 0.f};
#pragma unroll
    for (int ks = 0; ks < 8; ks++) {
      bs8 af = *(const bs8*)(hrow + ks * 32 + quad * 8);
#pragma unroll
      for (int s = 0; s < 8; s++) {
        bs8 bf = *(const bs8*)(W2Tc + (size_t)(s * 16 + ln) * 256 + ks * 32 + quad * 8);
        acc[s] = MFMA_BF16(af, bf, acc[s]);
      }
    }
    float ss[4] = {0.f, 0.f, 0.f, 0.f};
#pragma unroll
    for (int s = 0; s < 8; s++) {
      float b = b2c[s * 16 + ln];
#pragma unroll
      for (int r = 0; r < 4; r++) {
        acc[s][r] += b;
        ss[r] = fmaf(acc[s][r], acc[s][r], ss[r]);
      }
    }
#pragma unroll
    for (int r = 0; r < 4; r++) {
#pragma unroll
      for (int off = 1; off < 16; off <<= 1) ss[r] += __shfl_xor(ss[r], off, 64);
      float sc = 1.f / fmaxf(sqrtf(ss[r]), 1e-8f);
      const int lab = labels[rw + quad * 4 + r];
#pragma unroll
      for (int s = 0; s < 8; s++) {
        const unsigned short us = f2bf(acc[s][r] * sc);
        Zc[(size_t)(rw + quad * 4 + r) * 128 + s * 16 + ln] = us;
        if (lab > 0 && lab < 21) atomicAdd(&sS[lab * 128 + s * 16 + ln], bf2f(us));
      }
    }
  }

  __syncthreads();
  for (int i = t; i < 20 * 128; i += 256) {    // flush classes 1..20
    const float v = sS[128 + i];
    if (v != 0.f) atomicAdd(&Scls[128 + i], v);
  }
}

// ---------------- sim2: both heads, one launch, 4 gaps per block ----------------
// grid (64, 18). y<9: fg head; y>=9: cls head (y2=y-9).
// y2==0: d in {0,1,2,3} (incl diagonal); y2=1..7: d in {4*y2..4*y2+3};
// y2==8: d=32 only (bi<32). Off-diagonal tiles computed once: row sums -> rows
// of I (flushed once per block), col sums -> rows of J (flushed per tile).
__global__ void __launch_bounds__(256) sim2_kernel(
    const unsigned short* __restrict__ Zf, const unsigned short* __restrict__ Zc,
    const int* __restrict__ labels,
    float* __restrict__ rowD, float* __restrict__ rowN, float* __restrict__ rowS) {
  const int bi = blockIdx.x, y = blockIdx.y;
  const bool isfg = (y < 9);
  const int y2 = isfg ? y : y - 9;
  int dlo, dhi;
  if (y2 == 0)      { dlo = 0;      dhi = 3;      }
  else if (y2 < 8)  { dlo = y2 * 4; dhi = y2 * 4 + 3; }
  else              { dlo = 32;     dhi = 32; if (bi >= 32) return; }

  __shared__ __align__(16) char arena[19456];
  const int t = threadIdx.x;
  const int w = t >> 6, lane = t & 63, ln = lane & 15, quad = lane >> 4;
  const int rbase = bi * 128 + w * 32;

  if (isfg) {
    unsigned short* sZf = (unsigned short*)arena;          // 64*72*2 = 9216
    float* sFg = (float*)(arena + 9216);                   // 64*4    = 256
    float* sCol = (float*)(arena + 9472);                  // 4*2*4*16*2*4 = 4096

    bs8 afg[2][2];
    float fgr[2][4];
#pragma unroll
    for (int rs = 0; rs < 2; rs++) {
      const unsigned short* zf = Zf + (size_t)(rbase + rs * 16 + ln) * 64;
#pragma unroll
      for (int s = 0; s < 2; s++) afg[rs][s] = *(const bs8*)(zf + s * 32 + quad * 8);
#pragma unroll
      for (int r = 0; r < 4; r++)
        fgr[rs][r] = (labels[rbase + rs * 16 + quad * 4 + r] > 0) ? 1.f : 0.f;
    }

    float dacc[2][4] = {}, nacc[2][4] = {};     // row side, block-persistent

    for (int d = dlo; d <= dhi; d++) {
      const int bj = (bi + d) & 63;
      float cd[2][4] = {}, cn[2][4] = {};       // col side, per tile [ct][s]

#pragma unroll
      for (int ct = 0; ct < 2; ct++) {
        const int c0 = bj * 128 + ct * 64;
        __syncthreads();
#pragma unroll
        for (int i = 0; i < 2; i++) {
          int ch = t + i * 256;
          int j = ch >> 3, c8 = (ch & 7) * 8;
          *(bs8*)&sZf[j * 72 + c8] = *(const bs8*)(Zf + (size_t)(c0 + j) * 64 + c8);
        }
        if (t < 64) sFg[t] = (labels[c0 + t] > 0) ? 1.f : 0.f;
        __syncthreads();

#pragma unroll
        for (int s = 0; s < 4; s++) {
          const int lcol = s * 16 + ln;
          const float fgc = sFg[lcol];
          bs8 b0 = *(const bs8*)&sZf[lcol * 72 + quad * 8];
          bs8 b1 = *(const bs8*)&sZf[lcol * 72 + 32 + quad * 8];
#pragma unroll
          for (int rs = 0; rs < 2; rs++) {
            f4 c = {0.f, 0.f, 0.f, 0.f};
            c = MFMA_BF16(afg[rs][0], b0, c);
            c = MFMA_BF16(afg[rs][1], b1, c);
#pragma unroll
            for (int r = 0; r < 4; r++) {
              float e = EXP2F(c[r] * K_LOG2E);
              dacc[rs][r] += e;
              nacc[rs][r] = fmaf(fgc, e, nacc[rs][r]);
              cd[ct][s] += e;
              cn[ct][s] = fmaf(fgr[rs][r], e, cn[ct][s]);
            }
          }
        }
      }

      // col side -> rows of J (per tile)
      if (d != 0) {
#pragma unroll
        for (int ct = 0; ct < 2; ct++)
#pragma unroll
          for (int s = 0; s < 4; s++) {
            float dv = cd[ct][s], nv = cn[ct][s];
#pragma unroll
            for (int off = 16; off < 64; off <<= 1) {
              dv += __shfl_xor(dv, off, 64);
              nv += __shfl_xor(nv, off, 64);
            }
            if (quad == 0) {
              const int idx = (((w * 2 + ct) * 4 + s) * 16 + ln) * 2;
              sCol[idx] = dv;
              sCol[idx + 1] = nv;
            }
          }
        __syncthreads();
        if (t < 128) {
          const int ct = t >> 6, s = (t >> 4) & 3, lm = t & 15;
          float dv = 0.f, nv = 0.f;
#pragma unroll
          for (int ww = 0; ww < 4; ww++) {
            const int idx = (((ww * 2 + ct) * 4 + s) * 16 + lm) * 2;
            dv += sCol[idx];
            nv += sCol[idx + 1];
          }
          const int col = bj * 128 + t;
          atomicAdd(&rowD[col], dv);
          atomicAdd(&rowN[col], nv);
        }
      }
    }

    // row side -> rows of I (once per block)
#pragma unroll
    for (int rs = 0; rs < 2; rs++)
#pragma unroll
      for (int r = 0; r < 4; r++) {
        float dv = dacc[rs][r], nv = nacc[rs][r];
#pragma unroll
        for (int off = 1; off < 16; off <<= 1) {
          dv += __shfl_xor(dv, off, 64);
          nv += __shfl_xor(nv, off, 64);
        }
        if (ln == 0) {
          int row = rbase + rs * 16 + quad * 4 + r;
          atomicAdd(&rowD[row], dv);
          atomicAdd(&rowN[row], nv);
        }
      }
  } else {
    unsigned short* sZc = (unsigned short*)arena;          // 64*136*2 = 17408
    float* sCol = (float*)(arena + 17408);                 // 4*2*4*16*4 = 2048

    bs8 acl[2][4];
#pragma unroll
    for (int rs = 0; rs < 2; rs++) {
      const unsigned short* zc = Zc + (size_t)(rbase + rs * 16 + ln) * 128;
#pragma unroll
      for (int s = 0; s < 4; s++) acl[rs][s] = *(const bs8*)(zc + s * 32 + quad * 8);
    }

    float sacc[2][4] = {};                      // row side, block-persistent

    for (int d = dlo; d <= dhi; d++) {
      const int bj = (bi + d) & 63;
      float cs[2][4] = {};                      // col side, per tile [ct][s]

#pragma unroll
      for (int ct = 0; ct < 2; ct++) {
        const int c0 = bj * 128 + ct * 64;
        __syncthreads();
#pragma unroll
        for (int i = 0; i < 4; i++) {
          int ch = t + i * 256;
          int j = ch >> 4, c8 = (ch & 15) * 8;
          *(bs8*)&sZc[j * 136 + c8] = *(const bs8*)(Zc + (size_t)(c0 + j) * 128 + c8);
        }
        __syncthreads();

#pragma unroll
        for (int s = 0; s < 4; s++) {
          const int lcol = s * 16 + ln;
          bs8 bc0 = *(const bs8*)&sZc[lcol * 136 + quad * 8];
          bs8 bc1 = *(const bs8*)&sZc[lcol * 136 + 32 + quad * 8];
          bs8 bc2 = *(const bs8*)&sZc[lcol * 136 + 64 + quad * 8];
          bs8 bc3 = *(const bs8*)&sZc[lcol * 136 + 96 + quad * 8];
#pragma unroll
          for (int rs = 0; rs < 2; rs++) {
            f4 c = {0.f, 0.f, 0.f, 0.f};
            c = MFMA_BF16(acl[rs][0], bc0, c);
            c = MFMA_BF16(acl[rs][1], bc1, c);
            c = MFMA_BF16(acl[rs][2], bc2, c);
            c = MFMA_BF16(acl[rs][3], bc3, c);
#pragma unroll
            for (int r = 0; r < 4; r++) {
              float e = EXP2F(c[r] * K_LOG2E);
              sacc[rs][r] += e;
              cs[ct][s] += e;
            }
          }
        }
      }

      if (d != 0) {
#pragma unroll
        for (int ct = 0; ct < 2; ct++)
#pragma unroll
          for (int s = 0; s < 4; s++) {
            float sv = cs[ct][s];
#pragma unroll
            for (int off = 16; off < 64; off <<= 1) sv += __shfl_xor(sv, off, 64);
            if (quad == 0) sCol[((w * 2 + ct) * 4 + s) * 16 + ln] = sv;
          }
        __syncthreads();
        if (t < 128) {
          const int ct = t >> 6, s = (t >> 4) & 3, lm = t & 15;
          float sv = 0.f;
#pragma unroll
          for (int ww = 0; ww < 4; ww++) sv += sCol[((ww * 2 + ct) * 4 + s) * 16 + lm];
          atomicAdd(&rowS[bj * 128 + t], sv);
        }
      }
    }

#pragma unroll
    for (int rs = 0; rs < 2; rs++)
#pragma unroll
      for (int r = 0; r < 4; r++) {
        float sv = sacc[rs][r];
#pragma unroll
        for (int off = 1; off < 16; off <<= 1) sv += __shfl_xor(sv, off, 64);
        if (ln == 0)
          atomicAdd(&rowS[rbase + rs * 16 + quad * 4 + r], sv);
      }
  }
}

// ---------------- per-row losses + reduction + fused writeout (ticket) ----------------
__global__ void __launch_bounds__(256) finalize_kernel(
    const unsigned short* __restrict__ Zf, const unsigned short* __restrict__ Zc,
    const int* __restrict__ labels, const float* __restrict__ ious,
    const float* __restrict__ rowD, const float* __restrict__ rowN,
    const float* __restrict__ rowS, const float* __restrict__ Scls,
    const int* __restrict__ hist, const int* __restrict__ nfg,
    float* __restrict__ scal, unsigned int* __restrict__ cnt,
    float* __restrict__ out) {
  __shared__ float red[4][4];
  const int t = threadIdx.x, w = t >> 6, lane = t & 63;
  float aw0 = 0.f, al0 = 0.f, aw1 = 0.f, al1 = 0.f;
  const int NFG = *nfg;
  for (int it = 0; it < 16; it++) {
    const int i = it * 512 + blockIdx.x * 4 + w;   // wave-uniform row
    const int lab = labels[i];
    if (lab > 0 && lab < 32) {                     // fg row
      const float iou = ious[i];
      const float iw = (iou > 0.5f) ? iou : 0.f;
      float dot = 0.f, ssq = 0.f;
#pragma unroll
      for (int p = 0; p < 2; p++) {
        const int k = lane + p * 64;
        const float z = bf2f(Zc[(size_t)i * 128 + k]);
        dot = fmaf(z, Scls[lab * 128 + k], dot);
        ssq = fmaf(z, z, ssq);
      }
      float zf = bf2f(Zf[(size_t)i * 64 + lane]);
      float ssqf = zf * zf;
#pragma unroll
      for (int off = 1; off < 64; off <<= 1) {
        dot += __shfl_xor(dot, off, 64);
        ssq += __shfl_xor(ssq, off, 64);
        ssqf += __shfl_xor(ssqf, off, 64);
      }
      if (lane == 0) {
        const float ef = EXP2F(K_LOG2E * ssqf);   // diag term exp(sim_ii/tau), fg head
        if (NFG - 1 > 0) {  // n_pos = NFG - 1 for fg rows
          const float D = rowD[i] - ef;
          const float Nn = rowN[i] - ef;
          const float loss = logf(D + 2e-8f) - logf(Nn + 1e-8f);
          aw0 += iw;
          al0 += iw * loss;
        }
        const int npc = hist[lab];
        if (npc > 0) {
          const float S = rowS[i] - EXP2F(K_LOG2E * ssq);  // remove cls diag
          const float logden = logf(S);
          // sum_log_p = sum_{pos,j!=i}(sim) - (npc-1)*logden + NEG(diag)
          const float slp = (dot - ssq) * 5.0f - (float)(npc - 1) * logden - 1e9f;
          aw1 += iw;
          al1 += iw * (-slp / ((float)npc + 1e-8f));
        }
      }
    }
  }
  if (lane == 0) { red[w][0] = aw0; red[w][1] = al0; red[w][2] = aw1; red[w][3] = al1; }
  __syncthreads();
  if (t < 4) atomicAdd(&scal[t], red[0][t] + red[1][t] + red[2][t] + red[3][t]);
  __syncthreads();
  if (t == 0) {
    __threadfence();
    const unsigned int ticket = atomicAdd(cnt, 1u);
    if (ticket == gridDim.x - 1) {               // last block: fused writeout
      __threadfence();
      const float s0 = atomicAdd(&scal[0], 0.f);
      const float s1 = atomicAdd(&scal[1], 0.f);
      const float s2 = atomicAdd(&scal[2], 0.f);
      const float s3 = atomicAdd(&scal[3], 0.f);
      out[0] = s1 / (s0 + 1e-8f);
      out[1] = s3 / (s2 + 1e-8f);
    }
  }
}

// ---------------- launch ----------------
extern "C" void kernel_launch(void* const* d_in, const int* in_sizes, int n_in,
                              void* d_out, int out_size, void* d_ws, size_t ws_size,
                              hipStream_t stream) {
  (void)in_sizes; (void)n_in; (void)out_size; (void)ws_size;
  const float* roi    = (const float*)d_in[0];
  const int*   labels = (const int*)d_in[1];
  const float* ious   = (const float*)d_in[2];
  const float* fgw1   = (const float*)d_in[3];
  const float* fgb1   = (const float*)d_in[4];
  const float* fgw2   = (const float*)d_in[5];
  const float* fgb2   = (const float*)d_in[6];
  const float* clsw1  = (const float*)d_in[7];
  const float* clsb1  = (const float*)d_in[8];
  const float* clsw2  = (const float*)d_in[9];
  const float* clsb2  = (const float*)d_in[10];

  char* ws = (char*)d_ws;
  unsigned short* W1T  = (unsigned short*)(ws + O_W1T);
  unsigned short* W2Tf = (unsigned short*)(ws + O_W2TF);
  unsigned short* W2Tc = (unsigned short*)(ws + O_W2TC);
  unsigned short* Hb   = (unsigned short*)(ws + O_H);
  unsigned short* Zf   = (unsigned short*)(ws + O_ZF);
  unsigned short* Zc   = (unsigned short*)(ws + O_ZC);
  float* Scls = (float*)(ws + O_SCLS);
  float* rowD = (float*)(ws + O_ROWD);
  float* rowN = (float*)(ws + O_ROWN);
  float* rowS = (float*)(ws + O_ROWS);
  float* scal = (float*)(ws + O_SCAL);
  unsigned int* cnt = (unsigned int*)(ws + O_CNT);
  int* hist = (int*)(ws + O_HIST);
  int* nfg  = (int*)(ws + O_NFG);
  float* out = (float*)d_out;

  hipLaunchKernelGGL(prep_kernel, dim3(254), dim3(256), 0, stream,
                     fgw1, clsw1, fgw2, clsw2, labels, W1T, W2Tf, W2Tc,
                     hist, nfg, (float*)(ws + O_SCLS));
  hipLaunchKernelGGL(gemm1_kernel, dim3(128, 4), dim3(512), 0, stream,
                     roi, W1T, fgb1, clsb1, Hb);
  hipLaunchKernelGGL(gemm2_kernel, dim3(256), dim3(256), 0, stream,
                     Hb, W2Tf, W2Tc, fgb2, clsb2, labels, Zf, Zc, Scls);
  hipLaunchKernelGGL(sim2_kernel, dim3(64, 18), dim3(256), 0, stream,
                     Zf, Zc, labels, rowD, rowN, rowS);
  hipLaunchKernelGGL(finalize_kernel, dim3(128), dim3(256), 0, stream,
                     Zf, Zc, labels, ious, rowD, rowN, rowS, Scls, hist, nfg,
                     scal, cnt, out);
}

// Round 15
// 199.331 us; speedup vs baseline: 1.1278x; 1.0116x over previous
//
#include <hip/hip_runtime.h>

// MultiHeadContrastive on MI355X (gfx950).
// prep (fused zero + weight transpose/convert + label meta)
//   -> GEMM1 (X@W1+b, relu, bf16 H; 8 waves/block, BK=64, reg-prefetch)
//   -> GEMM2 (+bias, L2-normalize, bf16 Z; FUSED class sums S_c via LDS)
//   -> sim2: ONE launch, symmetric tile-pairs, 4 gaps per block, SPLIT HEADS,
//        FULL-WIDTH J-tile staging (128 cols per barrier pair: 3 barriers/gap
//        instead of 5; col accumulators unchanged at 8 floats -> no VGPR growth)
//   -> finalize (per-row losses, diag corrections, weighted reduce,
//                FUSED writeout via last-block ticket).           5 launches.

typedef __attribute__((ext_vector_type(8))) short bs8;   // 8 x bf16 (4 VGPRs)
typedef __attribute__((ext_vector_type(4))) float f4;    // MFMA accumulator

#define MFMA_BF16(a, b, c) __builtin_amdgcn_mfma_f32_16x16x32_bf16((a), (b), (c), 0, 0, 0)

#if defined(__has_builtin)
#if __has_builtin(__builtin_amdgcn_exp2f)
#define EXP2F(x) __builtin_amdgcn_exp2f(x)
#endif
#endif
#ifndef EXP2F
#define EXP2F(x) exp2f(x)
#endif

#define K_LOG2E 7.2134752044448170f   // 5 * log2(e), for exp(sim/tau) = 2^(c*K)

__device__ __forceinline__ unsigned short f2bf(float f) {
  unsigned int u = __float_as_uint(f);
  u = (u + 0x7fffu + ((u >> 16) & 1u)) >> 16;   // RNE
  return (unsigned short)u;
}
__device__ __forceinline__ float bf2f(unsigned short s) {
  return __uint_as_float(((unsigned int)s) << 16);
}

// ---------------- workspace layout (bytes) ----------------
constexpr size_t O_W1T  = 0;          // 512x1024 bf16 (rows 0..255 fg, 256..511 cls), W1T[n][k]
constexpr size_t O_W2TF = 1048576;    // 64x256 bf16, W2Tf[d][h]
constexpr size_t O_W2TC = 1081344;    // 128x256 bf16
constexpr size_t O_H    = 1146880;    // 8192x512 bf16 (cols 0..255 fg-h, 256..511 cls-h)
constexpr size_t O_ZF   = 9535488;    // 8192x64 bf16 normalized
constexpr size_t O_ZC   = 10584064;   // 8192x128 bf16 normalized
constexpr size_t O_SCLS = 12681216;   // 32x128 f32 class sums (rows 1..20 used;
                                      //   row 31 col 0 = finalize ticket) [zeroed]
constexpr size_t O_ROWD = 12697600;   // 8192 f32 denom (fg head)   [zeroed]
constexpr size_t O_ROWN = 12730368;   // 8192 f32 numer (fg head)   [zeroed]
constexpr size_t O_ROWS = 12763136;   // 8192 f32 sum-exp (cls)     [zeroed]
constexpr size_t O_SCAL = 12795904;   // 4 f32: w_fg, wl_fg, w_c, wl_c [zeroed]
constexpr size_t O_HIST = 12795920;   // 32 int  (direct store by prep meta block)
constexpr size_t O_NFG  = 12796048;   // 1 int   (direct store by prep meta block)
constexpr size_t O_CNT  = O_SCLS + 31 * 128 * 4;   // ticket counter (in zeroed Scls row 31)
constexpr int ZERO_WORDS = (int)((O_SCAL + 16 - O_SCLS) / 4);  // 28676

// ---------------- prep: fused zero + transpose/convert + meta ----------------
// blocks 0..139: weight transpose tiles; block 140: label meta; 141..253: zero.
__global__ void __launch_bounds__(256) prep_kernel(
    const float* __restrict__ fgw1, const float* __restrict__ clsw1,
    const float* __restrict__ fgw2, const float* __restrict__ clsw2,
    const int* __restrict__ labels,
    unsigned short* __restrict__ W1T, unsigned short* __restrict__ W2Tf,
    unsigned short* __restrict__ W2Tc,
    int* __restrict__ hist, int* __restrict__ nfg, float* __restrict__ zp) {
  const int b = blockIdx.x;
  const int t = threadIdx.x;

  if (b >= 141) {                     // ---- zero accumulators ----
    const int i = (b - 141) * 256 + t;
    if (i < ZERO_WORDS) zp[i] = 0.f;
    return;
  }
  if (b == 140) {                     // ---- meta: hist + nfg, single block ----
    __shared__ int sh[33];
    if (t < 33) sh[t] = 0;
    __syncthreads();
    for (int it = 0; it < 32; it++) {
      const int lab = labels[it * 256 + t];
      if (lab >= 0 && lab < 32) atomicAdd(&sh[lab], 1);   // ~ignore
      if (lab > 0) atomicAdd(&sh[32], 1);                 // fg count
    }
    __syncthreads();
    if (t < 32) hist[t] = sh[t];
    if (t == 32) *nfg = sh[32];
    return;
  }
  // ---- weight transpose + f32->bf16 ----
  // m0: 64 tiles, m1: 64, m2: 4, m3: 8  (total 140)
  int m, tb;
  if (b < 64)       { m = 0; tb = b; }
  else if (b < 128) { m = 1; tb = b - 64; }
  else if (b < 132) { m = 2; tb = b - 128; }
  else              { m = 3; tb = b - 132; }
  __shared__ float tile[64][65];
  const float* src;
  unsigned short* dst;
  int R, C;
  if (m == 0)      { src = fgw1;  dst = W1T;              R = 1024; C = 256; }
  else if (m == 1) { src = clsw1; dst = W1T + 256 * 1024; R = 1024; C = 256; }
  else if (m == 2) { src = fgw2;  dst = W2Tf;             R = 256;  C = 64;  }
  else             { src = clsw2; dst = W2Tc;             R = 256;  C = 128; }
  const int cT = C >> 6;
  const int r0 = (tb / cT) << 6, c0 = (tb % cT) << 6;
  {
    const int rr = t >> 4, cc = (t & 15) << 2;
#pragma unroll
    for (int i = 0; i < 4; i++) {
      float4 v = *(const float4*)(src + (size_t)(r0 + rr + i * 16) * C + c0 + cc);
      tile[rr + i * 16][cc] = v.x; tile[rr + i * 16][cc + 1] = v.y;
      tile[rr + i * 16][cc + 2] = v.z; tile[rr + i * 16][cc + 3] = v.w;
    }
  }
  __syncthreads();
  {
    const int dr = t >> 2, dc = (t & 3) << 4;
    bs8 o0, o1;
#pragma unroll
    for (int j = 0; j < 8; j++) o0[j] = (short)f2bf(tile[dc + j][dr]);
#pragma unroll
    for (int j = 0; j < 8; j++) o1[j] = (short)f2bf(tile[dc + 8 + j][dr]);
    unsigned short* dp = dst + (size_t)(c0 + dr) * R + r0 + dc;
    *(bs8*)dp = o0;
    *(bs8*)(dp + 8) = o1;
  }
}

// ---------------- GEMM1: H = relu(X @ W1 + b1), both heads ----------------
// grid (128, 4) x 512 threads (8 waves): 64-row x 128-col tiles, BK=64.
// Wave w: rows (w&3)*16, cols (w>>2)*64. Register-prefetch pipelined.
__global__ void __launch_bounds__(512) gemm1_kernel(
    const float* __restrict__ X, const unsigned short* __restrict__ W1T,
    const float* __restrict__ b1f, const float* __restrict__ b1c,
    unsigned short* __restrict__ H) {
  __shared__ __align__(16) unsigned short lA[64 * 72];
  __shared__ __align__(16) unsigned short lB[128 * 72];
  const int t = threadIdx.x;
  const int w = t >> 6, lane = t & 63, ln = lane & 15, quad = lane >> 4;
  const int wr = (w & 3) * 16, wc = (w >> 2) * 64;
  const int m0 = blockIdx.x * 64, n0 = blockIdx.y * 128;

  const int ar = t >> 3, ac = (t & 7) * 8;
  const int br = t >> 2, bc = (t & 3) * 16;
  const float* xbase = X + (size_t)(m0 + ar) * 1024 + ac;
  const unsigned short* bbase = W1T + (size_t)(n0 + br) * 1024 + bc;

  float4 xa[2];
  bs8 xb[2];
#pragma unroll
  for (int i = 0; i < 2; i++) xa[i] = *(const float4*)(xbase + i * 4);
#pragma unroll
  for (int i = 0; i < 2; i++) xb[i] = *(const bs8*)(bbase + i * 8);

  f4 acc[4];
#pragma unroll
  for (int s = 0; s < 4; s++) acc[s] = (f4){0.f, 0.f, 0.f, 0.f};

  for (int ks = 0; ks < 16; ks++) {
    {
      bs8 av;
      av[0] = (short)f2bf(xa[0].x); av[1] = (short)f2bf(xa[0].y);
      av[2] = (short)f2bf(xa[0].z); av[3] = (short)f2bf(xa[0].w);
      av[4] = (short)f2bf(xa[1].x); av[5] = (short)f2bf(xa[1].y);
      av[6] = (short)f2bf(xa[1].z); av[7] = (short)f2bf(xa[1].w);
      *(bs8*)&lA[ar * 72 + ac] = av;
      unsigned short* bp = &lB[br * 72 + bc];
      *(bs8*)(bp) = xb[0];
      *(bs8*)(bp + 8) = xb[1];
    }
    __syncthreads();
    if (ks < 15) {
      const int k1 = (ks + 1) * 64;
#pragma unroll
      for (int i = 0; i < 2; i++) xa[i] = *(const float4*)(xbase + k1 + i * 4);
#pragma unroll
      for (int i = 0; i < 2; i++) xb[i] = *(const bs8*)(bbase + k1 + i * 8);
    }
#pragma unroll
    for (int kk = 0; kk < 2; kk++) {
      bs8 af = *(const bs8*)&lA[(wr + ln) * 72 + kk * 32 + quad * 8];
#pragma unroll
      for (int s = 0; s < 4; s++) {
        bs8 bf = *(const bs8*)&lB[(wc + s * 16 + ln) * 72 + kk * 32 + quad * 8];
        acc[s] = MFMA_BF16(af, bf, acc[s]);
      }
    }
    __syncthreads();
  }
#pragma unroll
  for (int s = 0; s < 4; s++) {
    const int n = n0 + wc + s * 16 + ln;
    const float b = (n < 256) ? b1f[n] : b1c[n - 256];
#pragma unroll
    for (int r = 0; r < 4; r++) {
      float v = fmaxf(acc[s][r] + b, 0.f);
      H[(size_t)(m0 + wr + quad * 4 + r) * 512 + n] = f2bf(v);
    }
  }
}

// ---------------- GEMM2: Z = normalize(H @ W2 + b2), FUSED class sums ----------------
// grid (256): 32 rows/block; waves 0,1 = fg head; waves 2,3 = cls head.
// cls waves also accumulate S_c partials into LDS sS[21][128]; block flushes
// nonzero entries with one global atomic each (classes 1..20 only).
__global__ void __launch_bounds__(256) gemm2_kernel(
    const unsigned short* __restrict__ H,
    const unsigned short* __restrict__ W2Tf, const unsigned short* __restrict__ W2Tc,
    const float* __restrict__ b2f, const float* __restrict__ b2c,
    const int* __restrict__ labels,
    unsigned short* __restrict__ Zf, unsigned short* __restrict__ Zc,
    float* __restrict__ Scls) {
  __shared__ float sS[21 * 128];
  const int t = threadIdx.x;
  for (int i = t; i < 21 * 128; i += 256) sS[i] = 0.f;
  __syncthreads();

  const int w = t >> 6, lane = t & 63, ln = lane & 15, quad = lane >> 4;
  const int rw = blockIdx.x * 32 + (w & 1) * 16;

  if (w < 2) {  // fg head: K=256 (H cols 0..255), N=64
    const unsigned short* hrow = H + (size_t)(rw + ln) * 512;
    f4 acc[4];
#pragma unroll
    for (int s = 0; s < 4; s++) acc[s] = (f4){0.f, 0.f, 0.f, 0.f};
#pragma unroll
    for (int ks = 0; ks < 8; ks++) {
      bs8 af = *(const bs8*)(hrow + ks * 32 + quad * 8);
#pragma unroll
      for (int s = 0; s < 4; s++) {
        bs8 bf = *(const bs8*)(W2Tf + (size_t)(s * 16 + ln) * 256 + ks * 32 + quad * 8);
        acc[s] = MFMA_BF16(af, bf, acc[s]);
      }
    }
    float ss[4] = {0.f, 0.f, 0.f, 0.f};
#pragma unroll
    for (int s = 0; s < 4; s++) {
      float b = b2f[s * 16 + ln];
#pragma unroll
      for (int r = 0; r < 4; r++) {
        acc[s][r] += b;
        ss[r] = fmaf(acc[s][r], acc[s][r], ss[r]);
      }
    }
#pragma unroll
    for (int r = 0; r < 4; r++) {
#pragma unroll
      for (int off = 1; off < 16; off <<= 1) ss[r] += __shfl_xor(ss[r], off, 64);
      float sc = 1.f / fmaxf(sqrtf(ss[r]), 1e-8f);
#pragma unroll
      for (int s = 0; s < 4; s++)
        Zf[(size_t)(rw + quad * 4 + r) * 64 + s * 16 + ln] = f2bf(acc[s][r] * sc);
    }
  } else {  // cls head: K=256 (H cols 256..511), N=128
    const unsigned short* hrow = H + (size_t)(rw + ln) * 512 + 256;
    f4 acc[8];
#pragma unroll
    for (int s = 0; s < 8; s++) acc[s] = (f4){0.f, 0.f, 0.f, 0.f};
#pragma unroll
    for (int ks = 0; ks < 8; ks++) {
      bs8 af = *(const bs8*)(hrow + ks * 32 + quad * 8);
#pragma unroll
      for (int s = 0; s < 8; s++) {
        bs8 bf = *(const bs8*)(W2Tc + (size_t)(s * 16 + ln) * 256 + ks * 32 + quad * 8);
        acc[s] = MFMA_BF16(af, bf, acc[s]);
      }
    }
    float ss[4] = {0.f, 0.f, 0.f, 0.f};
#pragma unroll
    for (int s = 0; s < 8; s++) {
      float b = b2c[s * 16 + ln];
#pragma unroll
      for (int r = 0; r < 4; r++) {
        acc[s][r] += b;
        ss[r] = fmaf(acc[s][r], acc[s][r], ss[r]);
      }
    }
#pragma unroll
    for (int r = 0; r < 4; r++) {
#pragma unroll
      for (int off = 1; off < 16; off <<= 1) ss[r] += __shfl_xor(ss[r], off, 64);
      float sc = 1.f / fmaxf(sqrtf(ss[r]), 1e-8f);
      const int lab = labels[rw + quad * 4 + r];
#pragma unroll
      for (int s = 0; s < 8; s++) {
        const unsigned short us = f2bf(acc[s][r] * sc);
        Zc[(size_t)(rw + quad * 4 + r) * 128 + s * 16 + ln] = us;
        if (lab > 0 && lab < 21) atomicAdd(&sS[lab * 128 + s * 16 + ln], bf2f(us));
      }
    }
  }

  __syncthreads();
  for (int i = t; i < 20 * 128; i += 256) {    // flush classes 1..20
    const float v = sS[128 + i];
    if (v != 0.f) atomicAdd(&Scls[128 + i], v);
  }
}

// ---------------- sim2: split heads, 4 gaps/block, FULL-WIDTH J staging ----------------
// grid (64, 18). y<9: fg head; y>=9: cls head (y2=y-9).
// y2==0: d in {0,1,2,3} (incl diagonal); y2=1..7: d in {4*y2..4*y2+3};
// y2==8: d=32 only (bi<32). Per gap: stage ALL 128 J-columns in one barrier
// pair (3 barriers/gap vs 5). Column sums accumulate per s=0..7 (same 8 regs
// as the old [ct][s]; column visit order unchanged -> bit-identical sums).
__global__ void __launch_bounds__(256) sim2_kernel(
    const unsigned short* __restrict__ Zf, const unsigned short* __restrict__ Zc,
    const int* __restrict__ labels,
    float* __restrict__ rowD, float* __restrict__ rowN, float* __restrict__ rowS) {
  const int bi = blockIdx.x, y = blockIdx.y;
  const bool isfg = (y < 9);
  const int y2 = isfg ? y : y - 9;
  int dlo, dhi;
  if (y2 == 0)      { dlo = 0;      dhi = 3;      }
  else if (y2 < 8)  { dlo = y2 * 4; dhi = y2 * 4 + 3; }
  else              { dlo = 32;     dhi = 32; if (bi >= 32) return; }

  __shared__ __align__(16) char arena[36864];
  const int t = threadIdx.x;
  const int w = t >> 6, lane = t & 63, ln = lane & 15, quad = lane >> 4;
  const int rbase = bi * 128 + w * 32;

  if (isfg) {
    unsigned short* sZf = (unsigned short*)arena;          // 128*72*2 = 18432
    float* sFg = (float*)(arena + 18432);                  // 128*4    = 512
    float* sCol = (float*)(arena + 18944);                 // 4*8*16*2*4 = 4096

    bs8 afg[2][2];
    float fgr[2][4];
#pragma unroll
    for (int rs = 0; rs < 2; rs++) {
      const unsigned short* zf = Zf + (size_t)(rbase + rs * 16 + ln) * 64;
#pragma unroll
      for (int s = 0; s < 2; s++) afg[rs][s] = *(const bs8*)(zf + s * 32 + quad * 8);
#pragma unroll
      for (int r = 0; r < 4; r++)
        fgr[rs][r] = (labels[rbase + rs * 16 + quad * 4 + r] > 0) ? 1.f : 0.f;
    }

    float dacc[2][4] = {}, nacc[2][4] = {};     // row side, block-persistent

    for (int d = dlo; d <= dhi; d++) {
      const int bj = (bi + d) & 63;
      const int c0 = bj * 128;
      float cd[8] = {}, cn[8] = {};             // col side, per gap (s = 0..7)

      __syncthreads();                          // prior gap's sCol readers done
#pragma unroll
      for (int i = 0; i < 4; i++) {             // stage 128 rows x 64 cols
        int ch = t + i * 256;
        int j = ch >> 3, c8 = (ch & 7) * 8;
        *(bs8*)&sZf[j * 72 + c8] = *(const bs8*)(Zf + (size_t)(c0 + j) * 64 + c8);
      }
      if (t < 128) sFg[t] = (labels[c0 + t] > 0) ? 1.f : 0.f;
      __syncthreads();

#pragma unroll
      for (int s = 0; s < 8; s++) {
        const int lcol = s * 16 + ln;
        const float fgc = sFg[lcol];
        bs8 b0 = *(const bs8*)&sZf[lcol * 72 + quad * 8];
        bs8 b1 = *(const bs8*)&sZf[lcol * 72 + 32 + quad * 8];
#pragma unroll
        for (int rs = 0; rs < 2; rs++) {
          f4 c = {0.f, 0.f, 0.f, 0.f};
          c = MFMA_BF16(afg[rs][0], b0, c);
          c = MFMA_BF16(afg[rs][1], b1, c);
#pragma unroll
          for (int r = 0; r < 4; r++) {
            float e = EXP2F(c[r] * K_LOG2E);
            dacc[rs][r] += e;
            nacc[rs][r] = fmaf(fgc, e, nacc[rs][r]);
            cd[s] += e;
            cn[s] = fmaf(fgr[rs][r], e, cn[s]);
          }
        }
      }

      // col side -> rows of J (per gap)
      if (d != 0) {
#pragma unroll
        for (int s = 0; s < 8; s++) {
          float dv = cd[s], nv = cn[s];
#pragma unroll
          for (int off = 16; off < 64; off <<= 1) {
            dv += __shfl_xor(dv, off, 64);
            nv += __shfl_xor(nv, off, 64);
          }
          if (quad == 0) {
            const int idx = ((w * 8 + s) * 16 + ln) * 2;
            sCol[idx] = dv;
            sCol[idx + 1] = nv;
          }
        }
        __syncthreads();
        if (t < 128) {
          const int s = t >> 4, lm = t & 15;
          float dv = 0.f, nv = 0.f;
#pragma unroll
          for (int ww = 0; ww < 4; ww++) {
            const int idx = ((ww * 8 + s) * 16 + lm) * 2;
            dv += sCol[idx];
            nv += sCol[idx + 1];
          }
          const int col = c0 + t;
          atomicAdd(&rowD[col], dv);
          atomicAdd(&rowN[col], nv);
        }
      }
    }

    // row side -> rows of I (once per block)
#pragma unroll
    for (int rs = 0; rs < 2; rs++)
#pragma unroll
      for (int r = 0; r < 4; r++) {
        float dv = dacc[rs][r], nv = nacc[rs][r];
#pragma unroll
        for (int off = 1; off < 16; off <<= 1) {
          dv += __shfl_xor(dv, off, 64);
          nv += __shfl_xor(nv, off, 64);
        }
        if (ln == 0) {
          int row = rbase + rs * 16 + quad * 4 + r;
          atomicAdd(&rowD[row], dv);
          atomicAdd(&rowN[row], nv);
        }
      }
  } else {
    unsigned short* sZc = (unsigned short*)arena;          // 128*136*2 = 34816
    float* sCol = (float*)(arena + 34816);                 // 4*8*16*4 = 2048

    bs8 acl[2][4];
#pragma unroll
    for (int rs = 0; rs < 2; rs++) {
      const unsigned short* zc = Zc + (size_t)(rbase + rs * 16 + ln) * 128;
#pragma unroll
      for (int s = 0; s < 4; s++) acl[rs][s] = *(const bs8*)(zc + s * 32 + quad * 8);
    }

    float sacc[2][4] = {};                      // row side, block-persistent

    for (int d = dlo; d <= dhi; d++) {
      const int bj = (bi + d) & 63;
      const int c0 = bj * 128;
      float cs[8] = {};                         // col side, per gap (s = 0..7)

      __syncthreads();                          // prior gap's sCol readers done
#pragma unroll
      for (int i = 0; i < 8; i++) {             // stage 128 rows x 128 cols
        int ch = t + i * 256;
        int j = ch >> 4, c8 = (ch & 15) * 8;
        *(bs8*)&sZc[j * 136 + c8] = *(const bs8*)(Zc + (size_t)(c0 + j) * 128 + c8);
      }
      __syncthreads();

#pragma unroll
      for (int s = 0; s < 8; s++) {
        const int lcol = s * 16 + ln;
        bs8 bc0 = *(const bs8*)&sZc[lcol * 136 + quad * 8];
        bs8 bc1 = *(const bs8*)&sZc[lcol * 136 + 32 + quad * 8];
        bs8 bc2 = *(const bs8*)&sZc[lcol * 136 + 64 + quad * 8];
        bs8 bc3 = *(const bs8*)&sZc[lcol * 136 + 96 + quad * 8];
#pragma unroll
        for (int rs = 0; rs < 2; rs++) {
          f4 c = {0.f, 0.f, 0.f, 0.f};
          c = MFMA_BF16(acl[rs][0], bc0, c);
          c = MFMA_BF16(acl[rs][1], bc1, c);
          c = MFMA_BF16(acl[rs][2], bc2, c);
          c = MFMA_BF16(acl[rs][3], bc3, c);
#pragma unroll
          for (int r = 0; r < 4; r++) {
            float e = EXP2F(c[r] * K_LOG2E);
            sacc[rs][r] += e;
            cs[s] += e;
          }
        }
      }

      if (d != 0) {
#pragma unroll
        for (int s = 0; s < 8; s++) {
          float sv = cs[s];
#pragma unroll
          for (int off = 16; off < 64; off <<= 1) sv += __shfl_xor(sv, off, 64);
          if (quad == 0) sCol[(w * 8 + s) * 16 + ln] = sv;
        }
        __syncthreads();
        if (t < 128) {
          const int s = t >> 4, lm = t & 15;
          float sv = 0.f;
#pragma unroll
          for (int ww = 0; ww < 4; ww++) sv += sCol[(ww * 8 + s) * 16 + lm];
          atomicAdd(&rowS[c0 + t], sv);
        }
      }
    }

#pragma unroll
    for (int rs = 0; rs < 2; rs++)
#pragma unroll
      for (int r = 0; r < 4; r++) {
        float sv = sacc[rs][r];
#pragma unroll
        for (int off = 1; off < 16; off <<= 1) sv += __shfl_xor(sv, off, 64);
        if (ln == 0)
          atomicAdd(&rowS[rbase + rs * 16 + quad * 4 + r], sv);
      }
  }
}

// ---------------- per-row losses + reduction + fused writeout (ticket) ----------------
__global__ void __launch_bounds__(256) finalize_kernel(
    const unsigned short* __restrict__ Zf, const unsigned short* __restrict__ Zc,
    const int* __restrict__ labels, const float* __restrict__ ious,
    const float* __restrict__ rowD, const float* __restrict__ rowN,
    const float* __restrict__ rowS, const float* __restrict__ Scls,
    const int* __restrict__ hist, const int* __restrict__ nfg,
    float* __restrict__ scal, unsigned int* __restrict__ cnt,
    float* __restrict__ out) {
  __shared__ float red[4][4];
  const int t = threadIdx.x, w = t >> 6, lane = t & 63;
  float aw0 = 0.f, al0 = 0.f, aw1 = 0.f, al1 = 0.f;
  const int NFG = *nfg;
  for (int it = 0; it < 16; it++) {
    const int i = it * 512 + blockIdx.x * 4 + w;   // wave-uniform row
    const int lab = labels[i];
    if (lab > 0 && lab < 32) {                     // fg row
      const float iou = ious[i];
      const float iw = (iou > 0.5f) ? iou : 0.f;
      float dot = 0.f, ssq = 0.f;
#pragma unroll
      for (int p = 0; p < 2; p++) {
        const int k = lane + p * 64;
        const float z = bf2f(Zc[(size_t)i * 128 + k]);
        dot = fmaf(z, Scls[lab * 128 + k], dot);
        ssq = fmaf(z, z, ssq);
      }
      float zf = bf2f(Zf[(size_t)i * 64 + lane]);
      float ssqf = zf * zf;
#pragma unroll
      for (int off = 1; off < 64; off <<= 1) {
        dot += __shfl_xor(dot, off, 64);
        ssq += __shfl_xor(ssq, off, 64);
        ssqf += __shfl_xor(ssqf, off, 64);
      }
      if (lane == 0) {
        const float ef = EXP2F(K_LOG2E * ssqf);   // diag term exp(sim_ii/tau), fg head
        if (NFG - 1 > 0) {  // n_pos = NFG - 1 for fg rows
          const float D = rowD[i] - ef;
          const float Nn = rowN[i] - ef;
          const float loss = logf(D + 2e-8f) - logf(Nn + 1e-8f);
          aw0 += iw;
          al0 += iw * loss;
        }
        const int npc = hist[lab];
        if (npc > 0) {
          const float S = rowS[i] - EXP2F(K_LOG2E * ssq);  // remove cls diag
          const float logden = logf(S);
          // sum_log_p = sum_{pos,j!=i}(sim) - (npc-1)*logden + NEG(diag)
          const float slp = (dot - ssq) * 5.0f - (float)(npc - 1) * logden - 1e9f;
          aw1 += iw;
          al1 += iw * (-slp / ((float)npc + 1e-8f));
        }
      }
    }
  }
  if (lane == 0) { red[w][0] = aw0; red[w][1] = al0; red[w][2] = aw1; red[w][3] = al1; }
  __syncthreads();
  if (t < 4) atomicAdd(&scal[t], red[0][t] + red[1][t] + red[2][t] + red[3][t]);
  __syncthreads();
  if (t == 0) {
    __threadfence();
    const unsigned int ticket = atomicAdd(cnt, 1u);
    if (ticket == gridDim.x - 1) {               // last block: fused writeout
      __threadfence();
      const float s0 = atomicAdd(&scal[0], 0.f);
      const float s1 = atomicAdd(&scal[1], 0.f);
      const float s2 = atomicAdd(&scal[2], 0.f);
      const float s3 = atomicAdd(&scal[3], 0.f);
      out[0] = s1 / (s0 + 1e-8f);
      out[1] = s3 / (s2 + 1e-8f);
    }
  }
}

// ---------------- launch ----------------
extern "C" void kernel_launch(void* const* d_in, const int* in_sizes, int n_in,
                              void* d_out, int out_size, void* d_ws, size_t ws_size,
                              hipStream_t stream) {
  (void)in_sizes; (void)n_in; (void)out_size; (void)ws_size;
  const float* roi    = (const float*)d_in[0];
  const int*   labels = (const int*)d_in[1];
  const float* ious   = (const float*)d_in[2];
  const float* fgw1   = (const float*)d_in[3];
  const float* fgb1   = (const float*)d_in[4];
  const float* fgw2   = (const float*)d_in[5];
  const float* fgb2   = (const float*)d_in[6];
  const float* clsw1  = (const float*)d_in[7];
  const float* clsb1  = (const float*)d_in[8];
  const float* clsw2  = (const float*)d_in[9];
  const float* clsb2  = (const float*)d_in[10];

  char* ws = (char*)d_ws;
  unsigned short* W1T  = (unsigned short*)(ws + O_W1T);
  unsigned short* W2Tf = (unsigned short*)(ws + O_W2TF);
  unsigned short* W2Tc = (unsigned short*)(ws + O_W2TC);
  unsigned short* Hb   = (unsigned short*)(ws + O_H);
  unsigned short* Zf   = (unsigned short*)(ws + O_ZF);
  unsigned short* Zc   = (unsigned short*)(ws + O_ZC);
  float* Scls = (float*)(ws + O_SCLS);
  float* rowD = (float*)(ws + O_ROWD);
  float* rowN = (float*)(ws + O_ROWN);
  float* rowS = (float*)(ws + O_ROWS);
  float* scal = (float*)(ws + O_SCAL);
  unsigned int* cnt = (unsigned int*)(ws + O_CNT);
  int* hist = (int*)(ws + O_HIST);
  int* nfg  = (int*)(ws + O_NFG);
  float* out = (float*)d_out;

  hipLaunchKernelGGL(prep_kernel, dim3(254), dim3(256), 0, stream,
                     fgw1, clsw1, fgw2, clsw2, labels, W1T, W2Tf, W2Tc,
                     hist, nfg, (float*)(ws + O_SCLS));
  hipLaunchKernelGGL(gemm1_kernel, dim3(128, 4), dim3(512), 0, stream,
                     roi, W1T, fgb1, clsb1, Hb);
  hipLaunchKernelGGL(gemm2_kernel, dim3(256), dim3(256), 0, stream,
                     Hb, W2Tf, W2Tc, fgb2, clsb2, labels, Zf, Zc, Scls);
  hipLaunchKernelGGL(sim2_kernel, dim3(64, 18), dim3(256), 0, stream,
                     Zf, Zc, labels, rowD, rowN, rowS);
  hipLaunchKernelGGL(finalize_kernel, dim3(128), dim3(256), 0, stream,
                     Zf, Zc, labels, ious, rowD, rowN, rowS, Scls, hist, nfg,
                     scal, cnt, out);
}